// Round 16
// baseline (83.448 us; speedup 1.0000x reference)
//
#include <hip/hip_runtime.h>

#define BB 8
#define CC 128
#define HH 64
#define WW 64
#define K2 9
#define NOFF 18
#define HW 4096          // HH*WW
#define NPIX 32768       // BB*HW
#define OPAD 32          // o padded to 32 (2 N-tiles)
#define KW 1152          // 9*128 weight row length per o
#define HP 66            // padded spatial dim
#define PSTRIDE (HP*HP*CC)   // elems per batch (padded)

#define TR_BLOCKS     4096  // 128 p-tiles x 4 c-tiles x 8 b
#define WPREP_BLOCKS  144   // 32*9*128 / 256
#define BORDER_BLOCKS 260
#define MFMA_BLOCKS   2048  // one 16-px M-tile each
#define SAMPLE_BLOCKS 2048

typedef __attribute__((ext_vector_type(8))) short bf16x8;
typedef __attribute__((ext_vector_type(4))) float f32x4;

__device__ __forceinline__ unsigned short f2bf(float f) {
    unsigned u = __float_as_uint(f);
    unsigned r = u + 0x7FFFu + ((u >> 16) & 1u);   // RNE
    return (unsigned short)(r >> 16);
}
__device__ __forceinline__ float bf2f(unsigned short h) {
    return __uint_as_float((unsigned)h << 16);
}

// ---------------------------------------------------------------------------
// K0: fused prep.
//  [0,TR)        : transpose x -> xPh/xPl (hi/lo, zero-padded [b][66][66][128])
//  [TR,+WPREP)   : weights -> wH/wL [o(32 pad)][j(9)][c(128)] bf16
//  [.., +BORDER) : zero the 1-px border of xPh/xPl
// ---------------------------------------------------------------------------
__global__ __launch_bounds__(256) void prep_transpose_kernel(
    const float* __restrict__ x, const float* __restrict__ offw,
    unsigned short* __restrict__ xPh, unsigned short* __restrict__ xPl,
    unsigned short* __restrict__ wH, unsigned short* __restrict__ wL)
{
    __shared__ float tile[32][33];
    int bi = blockIdx.x;
    int tid = threadIdx.x;
    if (bi < TR_BLOCKS) {
        int p0 = (bi & 127) * 32;
        int c0 = ((bi >> 7) & 3) * 32;
        int b  = bi >> 9;
        int tx = tid & 31;
        int ty = tid >> 5;                 // 0..7
#pragma unroll
        for (int i = 0; i < 4; ++i)
            tile[ty + i * 8][tx] =
                x[((size_t)(b * CC + c0 + ty + i * 8)) * HW + p0 + tx];
        __syncthreads();
#pragma unroll
        for (int i = 0; i < 4; ++i) {
            int p = p0 + ty + i * 8;
            int h = p >> 6, w = p & 63;
            float v = tile[tx][ty + i * 8];
            unsigned short hi = f2bf(v);
            unsigned short lo = f2bf(v - bf2f(hi));
            size_t pidx = ((size_t)b * HP * HP + (size_t)(h + 1) * HP + (w + 1)) * CC + c0 + tx;
            xPh[pidx] = hi;
            xPl[pidx] = lo;
        }
    } else if (bi < TR_BLOCKS + WPREP_BLOCKS) {
        int i = (bi - TR_BLOCKS) * 256 + tid;   // o*1152 + j*128 + c
        int o = i / KW;
        int rem = i - o * KW;
        int j = rem >> 7;
        int c = rem & 127;
        float v = (o < NOFF) ? offw[((size_t)o * CC + c) * K2 + j] : 0.f;
        unsigned short hi = f2bf(v);
        unsigned short lo = f2bf(v - bf2f(hi));
        wH[i] = hi;
        wL[i] = lo;
    } else {
        int i = (bi - TR_BLOCKS - WPREP_BLOCKS) * 256 + tid;   // 0..66559
        int bufsel = i >= 33280;
        int jj = i - bufsel * 33280;
        int cell = jj >> 4, q = jj & 15;
        int b = cell / 260, r = cell - b * 260;
        int hp, wp;
        if (r < 132) { hp = (r >= 66) ? (HP - 1) : 0; wp = (r >= 66) ? r - 66 : r; }
        else { int r2 = r - 132; wp = (r2 & 1) ? (HP - 1) : 0; hp = 1 + (r2 >> 1); }
        unsigned short* dst = bufsel ? xPl : xPh;
        uint4 z = {0u, 0u, 0u, 0u};
        *(uint4*)(dst + (((size_t)b * HP + hp) * HP + wp) * CC + q * 8) = z;
    }
}

// ---------------------------------------------------------------------------
// K1: offset conv as MFMA im2col GEMM — high-occupancy.
// Block = ONE 16-px M-tile x 4 waves (wave = one c-chunk, full 9 j).
// Grid = 2048 blocks (8/CU wanted). Unconditional padded loads. Small LDS
// reduce (8.7 KB) over c-chunks + bias + coord transform -> sgrid.
// ---------------------------------------------------------------------------
__global__ __launch_bounds__(256, 4) void offset_mfma_kernel(
    const unsigned short* __restrict__ xPh, const unsigned short* __restrict__ xPl,
    const unsigned short* __restrict__ wH, const unsigned short* __restrict__ wL,
    const float* __restrict__ offb, float2* __restrict__ sgrid)
{
    __shared__ float red[4][OPAD][17];   // 8.7 KB
    int bi = blockIdx.x;        // 0..2047
    int b = bi & 7;             // XCD-local batch
    int idx = bi >> 3;          // 0..255
    int h  = idx >> 2;          // 0..63
    int w0 = (idx & 3) * 16;    // 0/16/32/48
    int tid = threadIdx.x;
    int l = tid & 63;
    int cw = __builtin_amdgcn_readfirstlane(tid >> 6);   // 0..3 c-chunk
    int c0 = cw * 32;
    int row  = l & 15;          // A: M-row ; B: o-col
    int kseg = l >> 4;          // 0..3 (8 k-elems each)

    f32x4 acc0 = (f32x4){0.f, 0.f, 0.f, 0.f};
    f32x4 acc1 = (f32x4){0.f, 0.f, 0.f, 0.f};

    const unsigned short* xh = xPh + (size_t)b * PSTRIDE;
    const unsigned short* xl = xPl + (size_t)b * PSTRIDE;

#pragma unroll
    for (int j = 0; j < K2; ++j) {
        const int dh = j / 3;        // 0..2 (padding absorbs -1)
        const int dw = j % 3;
        int koff = j * CC + c0 + kseg * 8;
        bf16x8 Bh0 = *(const bf16x8*)(wH + (size_t)row * KW + koff);
        bf16x8 Bl0 = *(const bf16x8*)(wL + (size_t)row * KW + koff);
        bf16x8 Bh1 = *(const bf16x8*)(wH + (size_t)(row + 16) * KW + koff);
        bf16x8 Bl1 = *(const bf16x8*)(wL + (size_t)(row + 16) * KW + koff);
        size_t a = ((size_t)(h + dh) * HP + (w0 + row + dw)) * CC + c0 + kseg * 8;
        bf16x8 Ah = *(const bf16x8*)(xh + a);
        bf16x8 Al = *(const bf16x8*)(xl + a);
        acc0 = __builtin_amdgcn_mfma_f32_16x16x32_bf16(Ah, Bh0, acc0, 0, 0, 0);
        acc0 = __builtin_amdgcn_mfma_f32_16x16x32_bf16(Al, Bh0, acc0, 0, 0, 0);
        acc0 = __builtin_amdgcn_mfma_f32_16x16x32_bf16(Ah, Bl0, acc0, 0, 0, 0);
        acc1 = __builtin_amdgcn_mfma_f32_16x16x32_bf16(Ah, Bh1, acc1, 0, 0, 0);
        acc1 = __builtin_amdgcn_mfma_f32_16x16x32_bf16(Al, Bh1, acc1, 0, 0, 0);
        acc1 = __builtin_amdgcn_mfma_f32_16x16x32_bf16(Ah, Bl1, acc1, 0, 0, 0);
    }

    // C/D: col = lane&15 (= o), row-in-tile = (lane>>4)*4 + reg  [R13-verified]
#pragma unroll
    for (int r = 0; r < 4; ++r) {
        red[cw][row][kseg * 4 + r]      = acc0[r];
        red[cw][row + 16][kseg * 4 + r] = acc1[r];
    }
    __syncthreads();

    if (tid < 144) {
        int p = tid & 15;
        int t = tid >> 4;        // 0..8
        float sx = offb[t]
                 + red[0][t][p] + red[1][t][p] + red[2][t][p] + red[3][t][p];
        float sy = offb[t + K2]
                 + red[0][t + K2][p] + red[1][t + K2][p]
                 + red[2][t + K2][p] + red[3][t + K2][p];
        float base_x = -1.f + (2.f / (WW - 1)) * (float)(w0 + p);
        float base_y = -1.f + (2.f / (HH - 1)) * (float)h;
        float gx = ((sx + base_x + 1.f) * (float)WW - 1.f) * 0.5f;
        float gy = ((sy + base_y + 1.f) * (float)HH - 1.f) * 0.5f;
        sgrid[(size_t)t * NPIX + b * HW + h * WW + w0 + p] = make_float2(gx, gy);
    }
}

// ---------------------------------------------------------------------------
// K2: bilinear sample + tap-weighted sum, reading the PADDED bf16 buffer
// (indices packed as padded offsets; clamped coords always in-bounds).
// ---------------------------------------------------------------------------
__global__ __launch_bounds__(256, 4) void sample_kernel(
    const unsigned short* __restrict__ xPh, const float2* __restrict__ sgrid,
    const float* __restrict__ wk, float* __restrict__ out)
{
    __shared__ float4 recW[144];
    __shared__ int2   recI[144];
    __shared__ float  swkT[K2 * CC];
    __shared__ float  acc_s[16 * 132];

    int j = blockIdx.x;            // 0..2047
    int b = j & 7;
    int rem_base = (j >> 3) * 16;
    int h  = rem_base >> 6;
    int w0 = rem_base & 63;
    int tid = threadIdx.x;

    for (int i = tid; i < K2 * CC; i += 256) {
        int c = i / 9, t = i - c * 9;
        swkT[t * CC + c] = wk[i];
    }

    if (tid < 144) {
        int slot = tid & 15;
        int tap  = tid >> 4;
        int rem  = rem_base + slot;
        int pix  = b * HW + rem;
        float2 s = sgrid[(size_t)tap * NPIX + pix];
        float gx = s.x, gy = s.y;

        float x0f = floorf(gx), y0f = floorf(gy);
        float wx1 = gx - x0f, wx0 = 1.f - wx1;
        float wy1 = gy - y0f, wy0 = 1.f - wy1;
        int ix0 = (int)x0f, iy0 = (int)y0f;
        int ix1 = ix0 + 1,  iy1 = iy0 + 1;
        float ax0 = ((unsigned)ix0 < WW) ? wx0 : 0.f;
        float ax1 = ((unsigned)ix1 < WW) ? wx1 : 0.f;
        float ay0 = ((unsigned)iy0 < HH) ? wy0 : 0.f;
        float ay1 = ((unsigned)iy1 < HH) ? wy1 : 0.f;
        int cx0 = min(max(ix0, 0), WW - 1) + 1, cx1 = min(max(ix1, 0), WW - 1) + 1;
        int cy0 = min(max(iy0, 0), HH - 1) + 1, cy1 = min(max(iy1, 0), HH - 1) + 1;
        int o00 = cy0 * HP + cx0, o10 = cy0 * HP + cx1;
        int o01 = cy1 * HP + cx0, o11 = cy1 * HP + cx1;
        recW[tid] = make_float4(ax0 * ay0, ax1 * ay0, ax0 * ay1, ax1 * ay1);
        recI[tid] = make_int2(o00 | (o10 << 16), o01 | (o11 << 16));
    }
    __syncthreads();

    int c8   = (tid & 15) * 8;
    int slot = tid >> 4;           // 0..15

    const unsigned short* xb = xPh + (size_t)b * PSTRIDE;

    float acc[8];
#pragma unroll
    for (int i = 0; i < 8; ++i) acc[i] = 0.f;

#pragma unroll
    for (int t = 0; t < K2; ++t) {
        int r = t * 16 + slot;
        float4 wv = recW[r];
        int2   iv = recI[r];
        uint4 u00 = *(const uint4*)(xb + (((iv.x & 0xFFFF) << 7) + c8));
        uint4 u10 = *(const uint4*)(xb + (((iv.x >> 16)     << 7) + c8));
        uint4 u01 = *(const uint4*)(xb + (((iv.y & 0xFFFF) << 7) + c8));
        uint4 u11 = *(const uint4*)(xb + (((iv.y >> 16)     << 7) + c8));
        float4 wkA = *(const float4*)&swkT[t * CC + c8];
        float4 wkB = *(const float4*)&swkT[t * CC + c8 + 4];
        const unsigned* p00 = (const unsigned*)&u00;
        const unsigned* p10 = (const unsigned*)&u10;
        const unsigned* p01 = (const unsigned*)&u01;
        const unsigned* p11 = (const unsigned*)&u11;
#pragma unroll
        for (int g = 0; g < 4; ++g) {
            float v00a = __uint_as_float(p00[g] << 16);
            float v00b = __uint_as_float(p00[g] & 0xFFFF0000u);
            float v10a = __uint_as_float(p10[g] << 16);
            float v10b = __uint_as_float(p10[g] & 0xFFFF0000u);
            float v01a = __uint_as_float(p01[g] << 16);
            float v01b = __uint_as_float(p01[g] & 0xFFFF0000u);
            float v11a = __uint_as_float(p11[g] << 16);
            float v11b = __uint_as_float(p11[g] & 0xFFFF0000u);
            float bila = fmaf(v00a, wv.x, fmaf(v10a, wv.y, fmaf(v01a, wv.z, v11a * wv.w)));
            float bilb = fmaf(v00b, wv.x, fmaf(v10b, wv.y, fmaf(v01b, wv.z, v11b * wv.w)));
            float wka = (g < 2) ? ((g == 0) ? wkA.x : wkA.z)
                                : ((g == 2) ? wkB.x : wkB.z);
            float wkb = (g < 2) ? ((g == 0) ? wkA.y : wkA.w)
                                : ((g == 2) ? wkB.y : wkB.w);
            acc[g * 2]     = fmaf(bila, wka, acc[g * 2]);
            acc[g * 2 + 1] = fmaf(bilb, wkb, acc[g * 2 + 1]);
        }
    }

    *(float4*)&acc_s[slot * 132 + c8]     = make_float4(acc[0], acc[1], acc[2], acc[3]);
    *(float4*)&acc_s[slot * 132 + c8 + 4] = make_float4(acc[4], acc[5], acc[6], acc[7]);
    __syncthreads();
#pragma unroll
    for (int r = 0; r < 8; ++r) {
        int cs   = r * 16 + (tid >> 4);
        int wloc = tid & 15;
        out[((size_t)(b * CC + cs)) * HW + h * WW + w0 + wloc] = acc_s[wloc * 132 + cs];
    }
}

// ---------------------------------------------------------------------------
// Fallback (round-1 pipeline, needs only 2.36 MB ws) — defensive only.
// ---------------------------------------------------------------------------
__global__ __launch_bounds__(256) void offset_grid_kernel_fb(
    const float* __restrict__ x, const float* __restrict__ offw,
    const float* __restrict__ offb, float* __restrict__ grid)
{
    int idx = blockIdx.x * blockDim.x + threadIdx.x;
    if (idx >= NPIX) return;
    int w = idx & 63, h = (idx >> 6) & 63, b = idx >> 12;
    float acc[NOFF];
#pragma unroll
    for (int o = 0; o < NOFF; ++o) acc[o] = offb[o];
    for (int c = 0; c < CC; ++c) {
        const float* xp = x + ((size_t)(b * CC + c)) * HW;
        float xv[9];
#pragma unroll
        for (int dh = -1; dh <= 1; ++dh)
#pragma unroll
            for (int dw = -1; dw <= 1; ++dw) {
                int hh = h + dh, ww2 = w + dw;
                float v = 0.f;
                if (hh >= 0 && hh < HH && ww2 >= 0 && ww2 < WW) v = xp[hh * WW + ww2];
                xv[(dh + 1) * 3 + (dw + 1)] = v;
            }
#pragma unroll
        for (int o = 0; o < NOFF; ++o) {
            const float* wp = offw + (size_t)(o * CC + c) * 9;
#pragma unroll
            for (int jj = 0; jj < 9; ++jj) acc[o] = fmaf(xv[jj], wp[jj], acc[o]);
        }
    }
    float base_x = -1.f + (2.f / (WW - 1)) * (float)w;
    float base_y = -1.f + (2.f / (HH - 1)) * (float)h;
#pragma unroll
    for (int t = 0; t < K2; ++t) {
        float gx = ((acc[t]      + base_x + 1.f) * (float)WW - 1.f) * 0.5f;
        float gy = ((acc[K2 + t] + base_y + 1.f) * (float)HH - 1.f) * 0.5f;
        size_t gi = ((((size_t)b * K2 + t) * HH + h) * WW + w) * 2;
        grid[gi] = gx; grid[gi + 1] = gy;
    }
}

__global__ __launch_bounds__(256) void sample_kernel_fb(
    const float* __restrict__ x, const float* __restrict__ grid,
    const float* __restrict__ wk, float* __restrict__ out)
{
    int idx = blockIdx.x * blockDim.x + threadIdx.x;
    if (idx >= BB * CC * HW) return;
    int w = idx & 63, h = (idx >> 6) & 63;
    int c = (idx / HW) & 127, b = idx / (CC * HW);
    const float* xp = x + ((size_t)(b * CC + c)) * HW;
    const float2* gp = (const float2*)grid;
    float acc = 0.f;
#pragma unroll
    for (int t = 0; t < K2; ++t) {
        float2 g = gp[(((size_t)b * K2 + t)) * HW + h * WW + w];
        float gx = g.x, gy = g.y;
        float x0f = floorf(gx), y0f = floorf(gy);
        float wx1 = gx - x0f, wx0 = 1.f - wx1;
        float wy1 = gy - y0f, wy0 = 1.f - wy1;
        int ix0 = (int)x0f, iy0 = (int)y0f;
        int ix1 = ix0 + 1,  iy1 = iy0 + 1;
        float v00 = 0.f, v10 = 0.f, v01 = 0.f, v11 = 0.f;
        if ((unsigned)iy0 < HH) {
            const float* row = xp + (size_t)iy0 * WW;
            if ((unsigned)ix0 < WW) v00 = row[ix0];
            if ((unsigned)ix1 < WW) v10 = row[ix1];
        }
        if ((unsigned)iy1 < HH) {
            const float* row = xp + (size_t)iy1 * WW;
            if ((unsigned)ix0 < WW) v01 = row[ix0];
            if ((unsigned)ix1 < WW) v11 = row[ix1];
        }
        float bil = v00 * (wx0 * wy0) + v10 * (wx1 * wy0)
                  + v01 * (wx0 * wy1) + v11 * (wx1 * wy1);
        acc = fmaf(bil, wk[c * K2 + t], acc);
    }
    out[idx] = acc;
}

extern "C" void kernel_launch(void* const* d_in, const int* in_sizes, int n_in,
                              void* d_out, int out_size, void* d_ws, size_t ws_size,
                              hipStream_t stream) {
    const float* x    = (const float*)d_in[0];
    const float* offw = (const float*)d_in[1];
    const float* offb = (const float*)d_in[2];
    const float* wwk  = (const float*)d_in[3];
    float* out = (float*)d_out;

    const size_t SGRID_BYTES = (size_t)K2 * NPIX * sizeof(float2);            // 2.36 MB
    const size_t XP_BYTES    = (size_t)BB * PSTRIDE * sizeof(unsigned short); // 8.92 MB
    const size_t W_BYTES     = (size_t)OPAD * KW * sizeof(unsigned short);    // 73.7 KB
    const size_t NEED = SGRID_BYTES + 2 * XP_BYTES + 2 * W_BYTES;             // 20.3 MB

    if (ws_size < NEED) {
        float* grid = (float*)d_ws;
        hipLaunchKernelGGL(offset_grid_kernel_fb, dim3(NPIX / 256), dim3(256),
                           0, stream, x, offw, offb, grid);
        hipLaunchKernelGGL(sample_kernel_fb, dim3((BB * CC * HW) / 256), dim3(256),
                           0, stream, x, grid, wwk, out);
        return;
    }

    // ws: [sgrid][xPh][xPl][wH][wL]
    char* p = (char*)d_ws;
    float2*         sgrid = (float2*)p;                 p += SGRID_BYTES;
    unsigned short* xPh = (unsigned short*)p;           p += XP_BYTES;
    unsigned short* xPl = (unsigned short*)p;           p += XP_BYTES;
    unsigned short* wH  = (unsigned short*)p;           p += W_BYTES;
    unsigned short* wL  = (unsigned short*)p;

    hipLaunchKernelGGL(prep_transpose_kernel,
                       dim3(TR_BLOCKS + WPREP_BLOCKS + BORDER_BLOCKS), dim3(256),
                       0, stream, x, offw, xPh, xPl, wH, wL);
    hipLaunchKernelGGL(offset_mfma_kernel, dim3(MFMA_BLOCKS), dim3(256),
                       0, stream, xPh, xPl, wH, wL, offb, sgrid);
    hipLaunchKernelGGL(sample_kernel, dim3(SAMPLE_BLOCKS), dim3(256),
                       0, stream, xPh, sgrid, wwk, out);
}

// Round 18
// 61.419 us; speedup vs baseline: 1.3587x; 1.3587x over previous
//
#include <hip/hip_runtime.h>

#define BB 8
#define CC 128
#define HH 64
#define WW 64
#define K2 9
#define NOFF 18
#define HW 4096          // HH*WW
#define NPIX 32768       // BB*HW
#define OPAD 32          // o padded to 32 (2 N-tiles)
#define KW 1152          // 9*128 weight row length per o
#define HP 66            // padded spatial dim
#define PSTRIDE (HP*HP*CC)   // elems per batch (padded)

#define TR_BLOCKS     4096  // 128 p-tiles x 4 c-tiles x 8 b
#define WPREP_BLOCKS  144   // 32*9*128 / 256
#define BORDER_BLOCKS 260   // 2 bufs x 2080 cells x 16 uint4 / 256
#define SAMPLE_BLOCKS 2048

typedef __attribute__((ext_vector_type(8))) short bf16x8;
typedef __attribute__((ext_vector_type(4))) float f32x4;

__device__ __forceinline__ unsigned short f2bf(float f) {
    unsigned u = __float_as_uint(f);
    unsigned r = u + 0x7FFFu + ((u >> 16) & 1u);   // RNE
    return (unsigned short)(r >> 16);
}
__device__ __forceinline__ float bf2f(unsigned short h) {
    return __uint_as_float((unsigned)h << 16);
}

// ---------------------------------------------------------------------------
// K0: fused prep (R15-verified).
//  [0,TR)        : transpose x -> xPh/xPl (hi/lo, zero-padded [b][66][66][128])
//  [TR,+WPREP)   : weights -> wH/wL [o(32 pad)][j(9)][c(128)] bf16
//  [.., +BORDER) : zero the 1-px border of xPh/xPl
// ---------------------------------------------------------------------------
__global__ __launch_bounds__(256) void prep_transpose_kernel(
    const float* __restrict__ x, const float* __restrict__ offw,
    unsigned short* __restrict__ xPh, unsigned short* __restrict__ xPl,
    unsigned short* __restrict__ wH, unsigned short* __restrict__ wL)
{
    __shared__ float tile[32][33];
    int bi = blockIdx.x;
    int tid = threadIdx.x;
    if (bi < TR_BLOCKS) {
        int p0 = (bi & 127) * 32;
        int c0 = ((bi >> 7) & 3) * 32;
        int b  = bi >> 9;
        int tx = tid & 31;
        int ty = tid >> 5;                 // 0..7
#pragma unroll
        for (int i = 0; i < 4; ++i)
            tile[ty + i * 8][tx] =
                x[((size_t)(b * CC + c0 + ty + i * 8)) * HW + p0 + tx];
        __syncthreads();
#pragma unroll
        for (int i = 0; i < 4; ++i) {
            int p = p0 + ty + i * 8;
            int h = p >> 6, w = p & 63;
            float v = tile[tx][ty + i * 8];
            unsigned short hi = f2bf(v);
            unsigned short lo = f2bf(v - bf2f(hi));
            size_t pidx = ((size_t)b * HP * HP + (size_t)(h + 1) * HP + (w + 1)) * CC + c0 + tx;
            xPh[pidx] = hi;
            xPl[pidx] = lo;
        }
    } else if (bi < TR_BLOCKS + WPREP_BLOCKS) {
        int i = (bi - TR_BLOCKS) * 256 + tid;   // o*1152 + j*128 + c
        int o = i / KW;
        int rem = i - o * KW;
        int j = rem >> 7;
        int c = rem & 127;
        float v = (o < NOFF) ? offw[((size_t)o * CC + c) * K2 + j] : 0.f;
        unsigned short hi = f2bf(v);
        unsigned short lo = f2bf(v - bf2f(hi));
        wH[i] = hi;
        wL[i] = lo;
    } else {
        int i = (bi - TR_BLOCKS - WPREP_BLOCKS) * 256 + tid;   // 0..66559
        int bufsel = i >= 33280;
        int jj = i - bufsel * 33280;
        int cell = jj >> 4, q = jj & 15;
        int b = cell / 260, r = cell - b * 260;
        int hp, wp;
        if (r < 132) { hp = (r >= 66) ? (HP - 1) : 0; wp = (r >= 66) ? r - 66 : r; }
        else { int r2 = r - 132; wp = (r2 & 1) ? (HP - 1) : 0; hp = 1 + (r2 >> 1); }
        unsigned short* dst = bufsel ? xPl : xPh;
        uint4 z = {0u, 0u, 0u, 0u};
        *(uint4*)(dst + (((size_t)b * HP + hp) * HP + wp) * CC + q * 8) = z;
    }
}

// ---------------------------------------------------------------------------
// K1: offset conv as MFMA im2col GEMM — 3-TERM precision (verified 0.0039:
// Ah*Bh + Al*Bh + Ah*Bl), register double-buffer over j + sched_barrier so
// next-j's 12 loads are issued before this-j's 24 MFMAs (counted vmcnt
// pipeline, not per-load drains). launch_bounds(256,2): VGPR cap 256 so the
// dbuf can't be starved into the VGPR=32 serialization (R14/R16 signature).
// Block = one h-row x 4 waves (wave = c-chunk), acc[4 m][2 n], padded loads.
// ---------------------------------------------------------------------------
__global__ __launch_bounds__(256, 2) void offset_mfma_kernel(
    const unsigned short* __restrict__ xPh, const unsigned short* __restrict__ xPl,
    const unsigned short* __restrict__ wH, const unsigned short* __restrict__ wL,
    const float* __restrict__ offb, float2* __restrict__ sgrid)
{
    __shared__ float red[4][OPAD][65];   // 33.3 KB
    int jx = blockIdx.x;        // 0..511
    int b = jx & 7;             // XCD-local batch
    int h = jx >> 3;            // 0..63
    int tid = threadIdx.x;
    int l = tid & 63;
    int cw = __builtin_amdgcn_readfirstlane(tid >> 6);   // 0..3 c-chunk
    int c0 = cw * 32;
    int row  = l & 15;          // A: M-row ; B: o-col
    int kseg = l >> 4;          // 0..3 (8 k-elems each)

    f32x4 acc[4][2];
#pragma unroll
    for (int m = 0; m < 4; ++m)
#pragma unroll
        for (int n = 0; n < 2; ++n)
            acc[m][n] = (f32x4){0.f, 0.f, 0.f, 0.f};

    const unsigned short* xh = xPh + (size_t)b * PSTRIDE;
    const unsigned short* xl = xPl + (size_t)b * PSTRIDE;

    // register double-buffers (static [j&1] indexing, fully unrolled)
    bf16x8 Bb[2][4];    // {Bh0, Bh1, Bl0, Bl1}
    bf16x8 Ahb[2][4];   // hi A fragment per m-tile
    bf16x8 Alb[2][4];   // lo A fragment per m-tile

    // prologue: issue j = 0 loads
    {
        int koff = c0 + kseg * 8;                     // j=0: dh=0,dw=0
        Bb[0][0] = *(const bf16x8*)(wH + (size_t)row * KW + koff);
        Bb[0][1] = *(const bf16x8*)(wH + (size_t)(row + 16) * KW + koff);
        Bb[0][2] = *(const bf16x8*)(wL + (size_t)row * KW + koff);
        Bb[0][3] = *(const bf16x8*)(wL + (size_t)(row + 16) * KW + koff);
        size_t rbase = ((size_t)h * HP) * CC + c0 + kseg * 8;
#pragma unroll
        for (int m = 0; m < 4; ++m) {
            size_t a = rbase + (size_t)(m * 16 + row) * CC;
            Ahb[0][m] = *(const bf16x8*)(xh + a);
            Alb[0][m] = *(const bf16x8*)(xl + a);
        }
    }

#pragma unroll
    for (int j = 0; j < K2; ++j) {
        const int cur = j & 1;
        const int nxt = cur ^ 1;
        if (j + 1 < K2) {
            const int jn = j + 1;
            const int dh = jn / 3, dw = jn % 3;       // compile-time
            int koff = jn * CC + c0 + kseg * 8;
            Bb[nxt][0] = *(const bf16x8*)(wH + (size_t)row * KW + koff);
            Bb[nxt][1] = *(const bf16x8*)(wH + (size_t)(row + 16) * KW + koff);
            Bb[nxt][2] = *(const bf16x8*)(wL + (size_t)row * KW + koff);
            Bb[nxt][3] = *(const bf16x8*)(wL + (size_t)(row + 16) * KW + koff);
            size_t rbase = ((size_t)(h + dh) * HP + dw) * CC + c0 + kseg * 8;
#pragma unroll
            for (int m = 0; m < 4; ++m) {
                size_t a = rbase + (size_t)(m * 16 + row) * CC;
                Ahb[nxt][m] = *(const bf16x8*)(xh + a);
                Alb[nxt][m] = *(const bf16x8*)(xl + a);
            }
        }
        __builtin_amdgcn_sched_barrier(0);   // pin next-j loads above the MFMAs
#pragma unroll
        for (int m = 0; m < 4; ++m) {
            acc[m][0] = __builtin_amdgcn_mfma_f32_16x16x32_bf16(Ahb[cur][m], Bb[cur][0], acc[m][0], 0, 0, 0);
            acc[m][0] = __builtin_amdgcn_mfma_f32_16x16x32_bf16(Alb[cur][m], Bb[cur][0], acc[m][0], 0, 0, 0);
            acc[m][0] = __builtin_amdgcn_mfma_f32_16x16x32_bf16(Ahb[cur][m], Bb[cur][2], acc[m][0], 0, 0, 0);
            acc[m][1] = __builtin_amdgcn_mfma_f32_16x16x32_bf16(Ahb[cur][m], Bb[cur][1], acc[m][1], 0, 0, 0);
            acc[m][1] = __builtin_amdgcn_mfma_f32_16x16x32_bf16(Alb[cur][m], Bb[cur][1], acc[m][1], 0, 0, 0);
            acc[m][1] = __builtin_amdgcn_mfma_f32_16x16x32_bf16(Ahb[cur][m], Bb[cur][3], acc[m][1], 0, 0, 0);
        }
    }

    // C/D: col = lane&15 (= o), row-in-tile = (lane>>4)*4 + reg  [R13-verified]
#pragma unroll
    for (int m = 0; m < 4; ++m)
#pragma unroll
        for (int n = 0; n < 2; ++n)
#pragma unroll
            for (int r = 0; r < 4; ++r)
                red[cw][n * 16 + row][m * 16 + kseg * 4 + r] = acc[m][n][r];
    __syncthreads();

    for (int item = tid; item < 576; item += 256) {
        int p = item & 63;
        int t = item >> 6;       // 0..8
        float sx = offb[t]
                 + red[0][t][p] + red[1][t][p] + red[2][t][p] + red[3][t][p];
        float sy = offb[t + K2]
                 + red[0][t + K2][p] + red[1][t + K2][p]
                 + red[2][t + K2][p] + red[3][t + K2][p];
        float base_x = -1.f + (2.f / (WW - 1)) * (float)p;
        float base_y = -1.f + (2.f / (HH - 1)) * (float)h;
        float gx = ((sx + base_x + 1.f) * (float)WW - 1.f) * 0.5f;
        float gy = ((sy + base_y + 1.f) * (float)HH - 1.f) * 0.5f;
        sgrid[(size_t)t * NPIX + b * HW + h * WW + p] = make_float2(gx, gy);
    }
}

// ---------------------------------------------------------------------------
// K2: bilinear sample + tap-weighted sum from padded bf16 buffer
// (R16-verified: padded index packing, clamped coords always in-bounds).
// ---------------------------------------------------------------------------
__global__ __launch_bounds__(256, 4) void sample_kernel(
    const unsigned short* __restrict__ xPh, const float2* __restrict__ sgrid,
    const float* __restrict__ wk, float* __restrict__ out)
{
    __shared__ float4 recW[144];
    __shared__ int2   recI[144];
    __shared__ float  swkT[K2 * CC];
    __shared__ float  acc_s[16 * 132];

    int j = blockIdx.x;            // 0..2047
    int b = j & 7;
    int rem_base = (j >> 3) * 16;
    int h  = rem_base >> 6;
    int w0 = rem_base & 63;
    int tid = threadIdx.x;

    for (int i = tid; i < K2 * CC; i += 256) {
        int c = i / 9, t = i - c * 9;
        swkT[t * CC + c] = wk[i];
    }

    if (tid < 144) {
        int slot = tid & 15;
        int tap  = tid >> 4;
        int rem  = rem_base + slot;
        int pix  = b * HW + rem;
        float2 s = sgrid[(size_t)tap * NPIX + pix];
        float gx = s.x, gy = s.y;

        float x0f = floorf(gx), y0f = floorf(gy);
        float wx1 = gx - x0f, wx0 = 1.f - wx1;
        float wy1 = gy - y0f, wy0 = 1.f - wy1;
        int ix0 = (int)x0f, iy0 = (int)y0f;
        int ix1 = ix0 + 1,  iy1 = iy0 + 1;
        float ax0 = ((unsigned)ix0 < WW) ? wx0 : 0.f;
        float ax1 = ((unsigned)ix1 < WW) ? wx1 : 0.f;
        float ay0 = ((unsigned)iy0 < HH) ? wy0 : 0.f;
        float ay1 = ((unsigned)iy1 < HH) ? wy1 : 0.f;
        int cx0 = min(max(ix0, 0), WW - 1) + 1, cx1 = min(max(ix1, 0), WW - 1) + 1;
        int cy0 = min(max(iy0, 0), HH - 1) + 1, cy1 = min(max(iy1, 0), HH - 1) + 1;
        int o00 = cy0 * HP + cx0, o10 = cy0 * HP + cx1;
        int o01 = cy1 * HP + cx0, o11 = cy1 * HP + cx1;
        recW[tid] = make_float4(ax0 * ay0, ax1 * ay0, ax0 * ay1, ax1 * ay1);
        recI[tid] = make_int2(o00 | (o10 << 16), o01 | (o11 << 16));
    }
    __syncthreads();

    int c8   = (tid & 15) * 8;
    int slot = tid >> 4;           // 0..15

    const unsigned short* xb = xPh + (size_t)b * PSTRIDE;

    float acc[8];
#pragma unroll
    for (int i = 0; i < 8; ++i) acc[i] = 0.f;

#pragma unroll
    for (int t = 0; t < K2; ++t) {
        int r = t * 16 + slot;
        float4 wv = recW[r];
        int2   iv = recI[r];
        uint4 u00 = *(const uint4*)(xb + (((iv.x & 0xFFFF) << 7) + c8));
        uint4 u10 = *(const uint4*)(xb + (((iv.x >> 16)     << 7) + c8));
        uint4 u01 = *(const uint4*)(xb + (((iv.y & 0xFFFF) << 7) + c8));
        uint4 u11 = *(const uint4*)(xb + (((iv.y >> 16)     << 7) + c8));
        float4 wkA = *(const float4*)&swkT[t * CC + c8];
        float4 wkB = *(const float4*)&swkT[t * CC + c8 + 4];
        const unsigned* p00 = (const unsigned*)&u00;
        const unsigned* p10 = (const unsigned*)&u10;
        const unsigned* p01 = (const unsigned*)&u01;
        const unsigned* p11 = (const unsigned*)&u11;
#pragma unroll
        for (int g = 0; g < 4; ++g) {
            float v00a = __uint_as_float(p00[g] << 16);
            float v00b = __uint_as_float(p00[g] & 0xFFFF0000u);
            float v10a = __uint_as_float(p10[g] << 16);
            float v10b = __uint_as_float(p10[g] & 0xFFFF0000u);
            float v01a = __uint_as_float(p01[g] << 16);
            float v01b = __uint_as_float(p01[g] & 0xFFFF0000u);
            float v11a = __uint_as_float(p11[g] << 16);
            float v11b = __uint_as_float(p11[g] & 0xFFFF0000u);
            float bila = fmaf(v00a, wv.x, fmaf(v10a, wv.y, fmaf(v01a, wv.z, v11a * wv.w)));
            float bilb = fmaf(v00b, wv.x, fmaf(v10b, wv.y, fmaf(v01b, wv.z, v11b * wv.w)));
            float wka = (g < 2) ? ((g == 0) ? wkA.x : wkA.z)
                                : ((g == 2) ? wkB.x : wkB.z);
            float wkb = (g < 2) ? ((g == 0) ? wkA.y : wkA.w)
                                : ((g == 2) ? wkB.y : wkB.w);
            acc[g * 2]     = fmaf(bila, wka, acc[g * 2]);
            acc[g * 2 + 1] = fmaf(bilb, wkb, acc[g * 2 + 1]);
        }
    }

    *(float4*)&acc_s[slot * 132 + c8]     = make_float4(acc[0], acc[1], acc[2], acc[3]);
    *(float4*)&acc_s[slot * 132 + c8 + 4] = make_float4(acc[4], acc[5], acc[6], acc[7]);
    __syncthreads();
#pragma unroll
    for (int r = 0; r < 8; ++r) {
        int cs   = r * 16 + (tid >> 4);
        int wloc = tid & 15;
        out[((size_t)(b * CC + cs)) * HW + h * WW + w0 + wloc] = acc_s[wloc * 132 + cs];
    }
}

// ---------------------------------------------------------------------------
// Fallback (round-1 pipeline, needs only 2.36 MB ws) — defensive only.
// ---------------------------------------------------------------------------
__global__ __launch_bounds__(256) void offset_grid_kernel_fb(
    const float* __restrict__ x, const float* __restrict__ offw,
    const float* __restrict__ offb, float* __restrict__ grid)
{
    int idx = blockIdx.x * blockDim.x + threadIdx.x;
    if (idx >= NPIX) return;
    int w = idx & 63, h = (idx >> 6) & 63, b = idx >> 12;
    float acc[NOFF];
#pragma unroll
    for (int o = 0; o < NOFF; ++o) acc[o] = offb[o];
    for (int c = 0; c < CC; ++c) {
        const float* xp = x + ((size_t)(b * CC + c)) * HW;
        float xv[9];
#pragma unroll
        for (int dh = -1; dh <= 1; ++dh)
#pragma unroll
            for (int dw = -1; dw <= 1; ++dw) {
                int hh = h + dh, ww2 = w + dw;
                float v = 0.f;
                if (hh >= 0 && hh < HH && ww2 >= 0 && ww2 < WW) v = xp[hh * WW + ww2];
                xv[(dh + 1) * 3 + (dw + 1)] = v;
            }
#pragma unroll
        for (int o = 0; o < NOFF; ++o) {
            const float* wp = offw + (size_t)(o * CC + c) * 9;
#pragma unroll
            for (int jj = 0; jj < 9; ++jj) acc[o] = fmaf(xv[jj], wp[jj], acc[o]);
        }
    }
    float base_x = -1.f + (2.f / (WW - 1)) * (float)w;
    float base_y = -1.f + (2.f / (HH - 1)) * (float)h;
#pragma unroll
    for (int t = 0; t < K2; ++t) {
        float gx = ((acc[t]      + base_x + 1.f) * (float)WW - 1.f) * 0.5f;
        float gy = ((acc[K2 + t] + base_y + 1.f) * (float)HH - 1.f) * 0.5f;
        size_t gi = ((((size_t)b * K2 + t) * HH + h) * WW + w) * 2;
        grid[gi] = gx; grid[gi + 1] = gy;
    }
}

__global__ __launch_bounds__(256) void sample_kernel_fb(
    const float* __restrict__ x, const float* __restrict__ grid,
    const float* __restrict__ wk, float* __restrict__ out)
{
    int idx = blockIdx.x * blockDim.x + threadIdx.x;
    if (idx >= BB * CC * HW) return;
    int w = idx & 63, h = (idx >> 6) & 63;
    int c = (idx / HW) & 127, b = idx / (CC * HW);
    const float* xp = x + ((size_t)(b * CC + c)) * HW;
    const float2* gp = (const float2*)grid;
    float acc = 0.f;
#pragma unroll
    for (int t = 0; t < K2; ++t) {
        float2 g = gp[(((size_t)b * K2 + t)) * HW + h * WW + w];
        float gx = g.x, gy = g.y;
        float x0f = floorf(gx), y0f = floorf(gy);
        float wx1 = gx - x0f, wx0 = 1.f - wx1;
        float wy1 = gy - y0f, wy0 = 1.f - wy1;
        int ix0 = (int)x0f, iy0 = (int)y0f;
        int ix1 = ix0 + 1,  iy1 = iy0 + 1;
        float v00 = 0.f, v10 = 0.f, v01 = 0.f, v11 = 0.f;
        if ((unsigned)iy0 < HH) {
            const float* row = xp + (size_t)iy0 * WW;
            if ((unsigned)ix0 < WW) v00 = row[ix0];
            if ((unsigned)ix1 < WW) v10 = row[ix1];
        }
        if ((unsigned)iy1 < HH) {
            const float* row = xp + (size_t)iy1 * WW;
            if ((unsigned)ix0 < WW) v01 = row[ix0];
            if ((unsigned)ix1 < WW) v11 = row[ix1];
        }
        float bil = v00 * (wx0 * wy0) + v10 * (wx1 * wy0)
                  + v01 * (wx0 * wy1) + v11 * (wx1 * wy1);
        acc = fmaf(bil, wk[c * K2 + t], acc);
    }
    out[idx] = acc;
}

extern "C" void kernel_launch(void* const* d_in, const int* in_sizes, int n_in,
                              void* d_out, int out_size, void* d_ws, size_t ws_size,
                              hipStream_t stream) {
    const float* x    = (const float*)d_in[0];
    const float* offw = (const float*)d_in[1];
    const float* offb = (const float*)d_in[2];
    const float* wwk  = (const float*)d_in[3];
    float* out = (float*)d_out;

    const size_t SGRID_BYTES = (size_t)K2 * NPIX * sizeof(float2);            // 2.36 MB
    const size_t XP_BYTES    = (size_t)BB * PSTRIDE * sizeof(unsigned short); // 8.92 MB
    const size_t W_BYTES     = (size_t)OPAD * KW * sizeof(unsigned short);    // 73.7 KB
    const size_t NEED = SGRID_BYTES + 2 * XP_BYTES + 2 * W_BYTES;             // 20.3 MB

    if (ws_size < NEED) {
        float* grid = (float*)d_ws;
        hipLaunchKernelGGL(offset_grid_kernel_fb, dim3(NPIX / 256), dim3(256),
                           0, stream, x, offw, offb, grid);
        hipLaunchKernelGGL(sample_kernel_fb, dim3((BB * CC * HW) / 256), dim3(256),
                           0, stream, x, grid, wwk, out);
        return;
    }

    // ws: [sgrid][xPh][xPl][wH][wL]
    char* p = (char*)d_ws;
    float2*         sgrid = (float2*)p;                 p += SGRID_BYTES;
    unsigned short* xPh = (unsigned short*)p;           p += XP_BYTES;
    unsigned short* xPl = (unsigned short*)p;           p += XP_BYTES;
    unsigned short* wH  = (unsigned short*)p;           p += W_BYTES;
    unsigned short* wL  = (unsigned short*)p;

    hipLaunchKernelGGL(prep_transpose_kernel,
                       dim3(TR_BLOCKS + WPREP_BLOCKS + BORDER_BLOCKS), dim3(256),
                       0, stream, x, offw, xPh, xPl, wH, wL);
    hipLaunchKernelGGL(offset_mfma_kernel, dim3(512), dim3(256),
                       0, stream, xPh, xPl, wH, wL, offb, sgrid);
    hipLaunchKernelGGL(sample_kernel, dim3(SAMPLE_BLOCKS), dim3(256),
                       0, stream, xPh, sgrid, wwk, out);
}

// Round 19
// 45.617 us; speedup vs baseline: 1.8293x; 1.3464x over previous
//
#include <hip/hip_runtime.h>

#define BB 8
#define CC 128
#define HH 64
#define WW 64
#define K2 9
#define NOFF 18
#define HW 4096          // HH*WW
#define NPIX 32768       // BB*HW
#define OPAD 32          // o padded to 32 (2 N-tiles)
#define HP 66            // padded spatial dim
#define PSTRIDE (HP*HP*CC)   // elems per batch (padded)

#define TR_BLOCKS     4096  // 128 p-tiles x 4 c-tiles x 8 b
#define WF_BLOCKS     288   // 144 frags x 512 elems / 256
#define BORDER_BLOCKS 260   // 2 bufs x 2080 cells x 16 uint4 / 256
#define SAMPLE_BLOCKS 2048

#define GR_ROW 1056         // granules (16B) per row-set per buf: 66 px x 16
#define ROWSET_BYTES 33792  // 2 bufs x 1056 x 16

typedef __attribute__((ext_vector_type(8))) short bf16x8;
typedef __attribute__((ext_vector_type(4))) float f32x4;

__device__ __forceinline__ unsigned short f2bf(float f) {
    unsigned u = __float_as_uint(f);
    unsigned r = u + 0x7FFFu + ((u >> 16) & 1u);   // RNE
    return (unsigned short)(r >> 16);
}
__device__ __forceinline__ float bf2f(unsigned short h) {
    return __uint_as_float((unsigned)h << 16);
}

// ---------------------------------------------------------------------------
// K0: fused prep.
//  [0,TR)        : transpose x -> xPh/xPl (hi/lo, zero-padded [b][66][66][128])
//  [TR,+WF)      : weights -> wF fragment-major: fid = ((j*4+cw)*2+n)*2+buf,
//                  frag = 512 elems laid out lane*8+elem so conv B-loads are
//                  one contiguous 16B/lane (1 KB/wave) read.
//  [.., +BORDER) : zero the 1-px border of xPh/xPl
// ---------------------------------------------------------------------------
__global__ __launch_bounds__(256) void prep_transpose_kernel(
    const float* __restrict__ x, const float* __restrict__ offw,
    unsigned short* __restrict__ xPh, unsigned short* __restrict__ xPl,
    unsigned short* __restrict__ wF)
{
    __shared__ float tile[32][33];
    int bi = blockIdx.x;
    int tid = threadIdx.x;
    if (bi < TR_BLOCKS) {
        int p0 = (bi & 127) * 32;
        int c0 = ((bi >> 7) & 3) * 32;
        int b  = bi >> 9;
        int tx = tid & 31;
        int ty = tid >> 5;                 // 0..7
#pragma unroll
        for (int i = 0; i < 4; ++i)
            tile[ty + i * 8][tx] =
                x[((size_t)(b * CC + c0 + ty + i * 8)) * HW + p0 + tx];
        __syncthreads();
#pragma unroll
        for (int i = 0; i < 4; ++i) {
            int p = p0 + ty + i * 8;
            int h = p >> 6, w = p & 63;
            float v = tile[tx][ty + i * 8];
            unsigned short hi = f2bf(v);
            unsigned short lo = f2bf(v - bf2f(hi));
            size_t pidx = ((size_t)b * HP * HP + (size_t)(h + 1) * HP + (w + 1)) * CC + c0 + tx;
            xPh[pidx] = hi;
            xPl[pidx] = lo;
        }
    } else if (bi < TR_BLOCKS + WF_BLOCKS) {
        int e = (bi - TR_BLOCKS) * 256 + tid;   // 0..73727
        int fid = e >> 9;
        int r = e & 511;
        int lane = r >> 3;
        int elem = r & 7;
        int bufsel = fid & 1;
        int n   = (fid >> 1) & 1;
        int cwv = (fid >> 2) & 3;
        int j   = fid >> 4;
        int o = n * 16 + (lane & 15);
        int c = cwv * 32 + ((lane >> 4) << 3) + elem;
        float v = (o < NOFF) ? offw[((size_t)o * CC + c) * K2 + j] : 0.f;
        unsigned short hi = f2bf(v);
        wF[e] = bufsel ? f2bf(v - bf2f(hi)) : hi;
    } else {
        int i = (bi - TR_BLOCKS - WF_BLOCKS) * 256 + tid;   // 0..66559
        int bufsel = i >= 33280;
        int jj = i - bufsel * 33280;
        int cell = jj >> 4, q = jj & 15;
        int b = cell / 260, r = cell - b * 260;
        int hp, wp;
        if (r < 132) { hp = (r >= 66) ? (HP - 1) : 0; wp = (r >= 66) ? r - 66 : r; }
        else { int r2 = r - 132; wp = (r2 & 1) ? (HP - 1) : 0; hp = 1 + (r2 >> 1); }
        unsigned short* dst = bufsel ? xPl : xPh;
        uint4 z = {0u, 0u, 0u, 0u};
        *(uint4*)(dst + (((size_t)b * HP + hp) * HP + wp) * CC + q * 8) = z;
    }
}

// ---------------------------------------------------------------------------
// K1: offset conv as MFMA GEMM with LDS-staged A (canonical §5 structure).
// Block = one h-row x 4 waves (wave = c-chunk, 4 m-tiles). Per dh-group:
// stage row h+dh (hi+lo, XOR-swizzled cslot) via contiguous 1KB/wave loads
// -> barrier -> 3 j's: B from fragment-major wF (contiguous), A via
// ds_read_b128 (swizzle -> b128 bank floor). 3-term precision (verified).
// Epilogue: red[] aliased over the staging buffer, reduce + transform.
// ---------------------------------------------------------------------------
__global__ __launch_bounds__(256, 2) void offset_mfma_kernel(
    const unsigned short* __restrict__ xPh, const unsigned short* __restrict__ xPl,
    const unsigned short* __restrict__ wF,
    const float* __restrict__ offb, float2* __restrict__ sgrid)
{
    __shared__ __align__(16) unsigned char LDSB[ROWSET_BYTES];   // 33 KB
    int jx = blockIdx.x;        // 0..511
    int b = jx & 7;             // XCD-local batch
    int h = jx >> 3;            // 0..63
    int tid = threadIdx.x;
    int l = tid & 63;
    int cw = __builtin_amdgcn_readfirstlane(tid >> 6);   // 0..3 c-chunk
    int row  = l & 15;          // A: M-row ; B: o-col
    int kseg = l >> 4;          // 0..3 (8 k-elems each)
    int cslot = cw * 4 + kseg;  // 16B channel-slot within 128 ch

    f32x4 acc[4][2];
#pragma unroll
    for (int m = 0; m < 4; ++m)
#pragma unroll
        for (int n = 0; n < 2; ++n)
            acc[m][n] = (f32x4){0.f, 0.f, 0.f, 0.f};

    const unsigned short* xh = xPh + (size_t)b * PSTRIDE;
    const unsigned short* xl = xPl + (size_t)b * PSTRIDE;

#pragma unroll 1
    for (int dh = 0; dh < 3; ++dh) {
        if (dh) __syncthreads();            // prior compute done before restage
        // ---- stage row h+dh: hi (granules 0..1055) + lo (1056..2111) ----
        const unsigned short* rowh = xh + ((size_t)(h + dh) * HP) * CC;
        const unsigned short* rowl = xl + ((size_t)(h + dh) * HP) * CC;
#pragma unroll
        for (int it = 0; it < 9; ++it) {
            int G = it * 256 + tid;
            if (G < 2112) {
                int buf = G >= GR_ROW;
                int g = G - (buf ? GR_ROW : 0);
                int px = g >> 4, cg = g & 15;
                const unsigned short* src =
                    (buf ? rowl : rowh) + (size_t)px * CC + ((cg ^ (px & 7)) << 3);
                uint4 v = *(const uint4*)src;
                *(uint4*)(LDSB + (size_t)G * 16) = v;
            }
        }
        __syncthreads();
        // ---- compute 3 j's of this row ----
#pragma unroll
        for (int dw = 0; dw < 3; ++dw) {
            int j = dh * 3 + dw;
            int fbase = (j * 4 + cw) * 4;   // fid of {Bh0,Bl0,Bh1,Bl1}
            bf16x8 Bh0 = *(const bf16x8*)(wF + (size_t)(fbase + 0) * 512 + l * 8);
            bf16x8 Bl0 = *(const bf16x8*)(wF + (size_t)(fbase + 1) * 512 + l * 8);
            bf16x8 Bh1 = *(const bf16x8*)(wF + (size_t)(fbase + 2) * 512 + l * 8);
            bf16x8 Bl1 = *(const bf16x8*)(wF + (size_t)(fbase + 3) * 512 + l * 8);
#pragma unroll
            for (int m = 0; m < 4; ++m) {
                int px = m * 16 + row + dw;               // padded w coord
                int gA = px * 16 + (cslot ^ (px & 7));    // swizzled granule
                bf16x8 Ah = *(const bf16x8*)(LDSB + (size_t)gA * 16);
                bf16x8 Al = *(const bf16x8*)(LDSB + (size_t)(GR_ROW + gA) * 16);
                acc[m][0] = __builtin_amdgcn_mfma_f32_16x16x32_bf16(Ah, Bh0, acc[m][0], 0, 0, 0);
                acc[m][0] = __builtin_amdgcn_mfma_f32_16x16x32_bf16(Al, Bh0, acc[m][0], 0, 0, 0);
                acc[m][0] = __builtin_amdgcn_mfma_f32_16x16x32_bf16(Ah, Bl0, acc[m][0], 0, 0, 0);
                acc[m][1] = __builtin_amdgcn_mfma_f32_16x16x32_bf16(Ah, Bh1, acc[m][1], 0, 0, 0);
                acc[m][1] = __builtin_amdgcn_mfma_f32_16x16x32_bf16(Al, Bh1, acc[m][1], 0, 0, 0);
                acc[m][1] = __builtin_amdgcn_mfma_f32_16x16x32_bf16(Ah, Bl1, acc[m][1], 0, 0, 0);
            }
        }
    }

    // ---- epilogue: alias red[] over the staging buffer ----
    __syncthreads();
    float (*red)[OPAD][65] = (float (*)[OPAD][65])LDSB;   // 33280 B <= 33792
#pragma unroll
    for (int m = 0; m < 4; ++m)
#pragma unroll
        for (int n = 0; n < 2; ++n)
#pragma unroll
            for (int r = 0; r < 4; ++r)
                red[cw][n * 16 + row][m * 16 + kseg * 4 + r] = acc[m][n][r];
    __syncthreads();

    for (int item = tid; item < 576; item += 256) {
        int p = item & 63;
        int t = item >> 6;       // 0..8
        float sx = offb[t]
                 + red[0][t][p] + red[1][t][p] + red[2][t][p] + red[3][t][p];
        float sy = offb[t + K2]
                 + red[0][t + K2][p] + red[1][t + K2][p]
                 + red[2][t + K2][p] + red[3][t + K2][p];
        float base_x = -1.f + (2.f / (WW - 1)) * (float)p;
        float base_y = -1.f + (2.f / (HH - 1)) * (float)h;
        float gx = ((sx + base_x + 1.f) * (float)WW - 1.f) * 0.5f;
        float gy = ((sy + base_y + 1.f) * (float)HH - 1.f) * 0.5f;
        sgrid[(size_t)t * NPIX + b * HW + h * WW + p] = make_float2(gx, gy);
    }
}

// ---------------------------------------------------------------------------
// K2: bilinear sample + tap-weighted sum from padded bf16 buffer
// (R16/R18-verified: padded index packing, clamped coords always in-bounds).
// ---------------------------------------------------------------------------
__global__ __launch_bounds__(256, 4) void sample_kernel(
    const unsigned short* __restrict__ xPh, const float2* __restrict__ sgrid,
    const float* __restrict__ wk, float* __restrict__ out)
{
    __shared__ float4 recW[144];
    __shared__ int2   recI[144];
    __shared__ float  swkT[K2 * CC];
    __shared__ float  acc_s[16 * 132];

    int j = blockIdx.x;            // 0..2047
    int b = j & 7;
    int rem_base = (j >> 3) * 16;
    int h  = rem_base >> 6;
    int w0 = rem_base & 63;
    int tid = threadIdx.x;

    for (int i = tid; i < K2 * CC; i += 256) {
        int c = i / 9, t = i - c * 9;
        swkT[t * CC + c] = wk[i];
    }

    if (tid < 144) {
        int slot = tid & 15;
        int tap  = tid >> 4;
        int rem  = rem_base + slot;
        int pix  = b * HW + rem;
        float2 s = sgrid[(size_t)tap * NPIX + pix];
        float gx = s.x, gy = s.y;

        float x0f = floorf(gx), y0f = floorf(gy);
        float wx1 = gx - x0f, wx0 = 1.f - wx1;
        float wy1 = gy - y0f, wy0 = 1.f - wy1;
        int ix0 = (int)x0f, iy0 = (int)y0f;
        int ix1 = ix0 + 1,  iy1 = iy0 + 1;
        float ax0 = ((unsigned)ix0 < WW) ? wx0 : 0.f;
        float ax1 = ((unsigned)ix1 < WW) ? wx1 : 0.f;
        float ay0 = ((unsigned)iy0 < HH) ? wy0 : 0.f;
        float ay1 = ((unsigned)iy1 < HH) ? wy1 : 0.f;
        int cx0 = min(max(ix0, 0), WW - 1) + 1, cx1 = min(max(ix1, 0), WW - 1) + 1;
        int cy0 = min(max(iy0, 0), HH - 1) + 1, cy1 = min(max(iy1, 0), HH - 1) + 1;
        int o00 = cy0 * HP + cx0, o10 = cy0 * HP + cx1;
        int o01 = cy1 * HP + cx0, o11 = cy1 * HP + cx1;
        recW[tid] = make_float4(ax0 * ay0, ax1 * ay0, ax0 * ay1, ax1 * ay1);
        recI[tid] = make_int2(o00 | (o10 << 16), o01 | (o11 << 16));
    }
    __syncthreads();

    int c8   = (tid & 15) * 8;
    int slot = tid >> 4;           // 0..15

    const unsigned short* xb = xPh + (size_t)b * PSTRIDE;

    float acc[8];
#pragma unroll
    for (int i = 0; i < 8; ++i) acc[i] = 0.f;

#pragma unroll
    for (int t = 0; t < K2; ++t) {
        int r = t * 16 + slot;
        float4 wv = recW[r];
        int2   iv = recI[r];
        uint4 u00 = *(const uint4*)(xb + (((iv.x & 0xFFFF) << 7) + c8));
        uint4 u10 = *(const uint4*)(xb + (((iv.x >> 16)     << 7) + c8));
        uint4 u01 = *(const uint4*)(xb + (((iv.y & 0xFFFF) << 7) + c8));
        uint4 u11 = *(const uint4*)(xb + (((iv.y >> 16)     << 7) + c8));
        float4 wkA = *(const float4*)&swkT[t * CC + c8];
        float4 wkB = *(const float4*)&swkT[t * CC + c8 + 4];
        const unsigned* p00 = (const unsigned*)&u00;
        const unsigned* p10 = (const unsigned*)&u10;
        const unsigned* p01 = (const unsigned*)&u01;
        const unsigned* p11 = (const unsigned*)&u11;
#pragma unroll
        for (int g = 0; g < 4; ++g) {
            float v00a = __uint_as_float(p00[g] << 16);
            float v00b = __uint_as_float(p00[g] & 0xFFFF0000u);
            float v10a = __uint_as_float(p10[g] << 16);
            float v10b = __uint_as_float(p10[g] & 0xFFFF0000u);
            float v01a = __uint_as_float(p01[g] << 16);
            float v01b = __uint_as_float(p01[g] & 0xFFFF0000u);
            float v11a = __uint_as_float(p11[g] << 16);
            float v11b = __uint_as_float(p11[g] & 0xFFFF0000u);
            float bila = fmaf(v00a, wv.x, fmaf(v10a, wv.y, fmaf(v01a, wv.z, v11a * wv.w)));
            float bilb = fmaf(v00b, wv.x, fmaf(v10b, wv.y, fmaf(v01b, wv.z, v11b * wv.w)));
            float wka = (g < 2) ? ((g == 0) ? wkA.x : wkA.z)
                                : ((g == 2) ? wkB.x : wkB.z);
            float wkb = (g < 2) ? ((g == 0) ? wkA.y : wkA.w)
                                : ((g == 2) ? wkB.y : wkB.w);
            acc[g * 2]     = fmaf(bila, wka, acc[g * 2]);
            acc[g * 2 + 1] = fmaf(bilb, wkb, acc[g * 2 + 1]);
        }
    }

    *(float4*)&acc_s[slot * 132 + c8]     = make_float4(acc[0], acc[1], acc[2], acc[3]);
    *(float4*)&acc_s[slot * 132 + c8 + 4] = make_float4(acc[4], acc[5], acc[6], acc[7]);
    __syncthreads();
#pragma unroll
    for (int r = 0; r < 8; ++r) {
        int cs   = r * 16 + (tid >> 4);
        int wloc = tid & 15;
        out[((size_t)(b * CC + cs)) * HW + h * WW + w0 + wloc] = acc_s[wloc * 132 + cs];
    }
}

// ---------------------------------------------------------------------------
// Fallback (round-1 pipeline, needs only 2.36 MB ws) — defensive only.
// ---------------------------------------------------------------------------
__global__ __launch_bounds__(256) void offset_grid_kernel_fb(
    const float* __restrict__ x, const float* __restrict__ offw,
    const float* __restrict__ offb, float* __restrict__ grid)
{
    int idx = blockIdx.x * blockDim.x + threadIdx.x;
    if (idx >= NPIX) return;
    int w = idx & 63, h = (idx >> 6) & 63, b = idx >> 12;
    float acc[NOFF];
#pragma unroll
    for (int o = 0; o < NOFF; ++o) acc[o] = offb[o];
    for (int c = 0; c < CC; ++c) {
        const float* xp = x + ((size_t)(b * CC + c)) * HW;
        float xv[9];
#pragma unroll
        for (int dh = -1; dh <= 1; ++dh)
#pragma unroll
            for (int dw = -1; dw <= 1; ++dw) {
                int hh = h + dh, ww2 = w + dw;
                float v = 0.f;
                if (hh >= 0 && hh < HH && ww2 >= 0 && ww2 < WW) v = xp[hh * WW + ww2];
                xv[(dh + 1) * 3 + (dw + 1)] = v;
            }
#pragma unroll
        for (int o = 0; o < NOFF; ++o) {
            const float* wp = offw + (size_t)(o * CC + c) * 9;
#pragma unroll
            for (int jj = 0; jj < 9; ++jj) acc[o] = fmaf(xv[jj], wp[jj], acc[o]);
        }
    }
    float base_x = -1.f + (2.f / (WW - 1)) * (float)w;
    float base_y = -1.f + (2.f / (HH - 1)) * (float)h;
#pragma unroll
    for (int t = 0; t < K2; ++t) {
        float gx = ((acc[t]      + base_x + 1.f) * (float)WW - 1.f) * 0.5f;
        float gy = ((acc[K2 + t] + base_y + 1.f) * (float)HH - 1.f) * 0.5f;
        size_t gi = ((((size_t)b * K2 + t) * HH + h) * WW + w) * 2;
        grid[gi] = gx; grid[gi + 1] = gy;
    }
}

__global__ __launch_bounds__(256) void sample_kernel_fb(
    const float* __restrict__ x, const float* __restrict__ grid,
    const float* __restrict__ wk, float* __restrict__ out)
{
    int idx = blockIdx.x * blockDim.x + threadIdx.x;
    if (idx >= BB * CC * HW) return;
    int w = idx & 63, h = (idx >> 6) & 63;
    int c = (idx / HW) & 127, b = idx / (CC * HW);
    const float* xp = x + ((size_t)(b * CC + c)) * HW;
    const float2* gp = (const float2*)grid;
    float acc = 0.f;
#pragma unroll
    for (int t = 0; t < K2; ++t) {
        float2 g = gp[(((size_t)b * K2 + t)) * HW + h * WW + w];
        float gx = g.x, gy = g.y;
        float x0f = floorf(gx), y0f = floorf(gy);
        float wx1 = gx - x0f, wx0 = 1.f - wx1;
        float wy1 = gy - y0f, wy0 = 1.f - wy1;
        int ix0 = (int)x0f, iy0 = (int)y0f;
        int ix1 = ix0 + 1,  iy1 = iy0 + 1;
        float v00 = 0.f, v10 = 0.f, v01 = 0.f, v11 = 0.f;
        if ((unsigned)iy0 < HH) {
            const float* row = xp + (size_t)iy0 * WW;
            if ((unsigned)ix0 < WW) v00 = row[ix0];
            if ((unsigned)ix1 < WW) v10 = row[ix1];
        }
        if ((unsigned)iy1 < HH) {
            const float* row = xp + (size_t)iy1 * WW;
            if ((unsigned)ix0 < WW) v01 = row[ix0];
            if ((unsigned)ix1 < WW) v11 = row[ix1];
        }
        float bil = v00 * (wx0 * wy0) + v10 * (wx1 * wy0)
                  + v01 * (wx0 * wy1) + v11 * (wx1 * wy1);
        acc = fmaf(bil, wk[c * K2 + t], acc);
    }
    out[idx] = acc;
}

extern "C" void kernel_launch(void* const* d_in, const int* in_sizes, int n_in,
                              void* d_out, int out_size, void* d_ws, size_t ws_size,
                              hipStream_t stream) {
    const float* x    = (const float*)d_in[0];
    const float* offw = (const float*)d_in[1];
    const float* offb = (const float*)d_in[2];
    const float* wwk  = (const float*)d_in[3];
    float* out = (float*)d_out;

    const size_t SGRID_BYTES = (size_t)K2 * NPIX * sizeof(float2);            // 2.36 MB
    const size_t XP_BYTES    = (size_t)BB * PSTRIDE * sizeof(unsigned short); // 8.92 MB
    const size_t WF_BYTES    = (size_t)144 * 512 * sizeof(unsigned short);    // 147 KB
    const size_t NEED = SGRID_BYTES + 2 * XP_BYTES + WF_BYTES;                // 20.3 MB

    if (ws_size < NEED) {
        float* grid = (float*)d_ws;
        hipLaunchKernelGGL(offset_grid_kernel_fb, dim3(NPIX / 256), dim3(256),
                           0, stream, x, offw, offb, grid);
        hipLaunchKernelGGL(sample_kernel_fb, dim3((BB * CC * HW) / 256), dim3(256),
                           0, stream, x, grid, wwk, out);
        return;
    }

    // ws: [sgrid][xPh][xPl][wF]
    char* p = (char*)d_ws;
    float2*         sgrid = (float2*)p;                 p += SGRID_BYTES;
    unsigned short* xPh = (unsigned short*)p;           p += XP_BYTES;
    unsigned short* xPl = (unsigned short*)p;           p += XP_BYTES;
    unsigned short* wF  = (unsigned short*)p;

    hipLaunchKernelGGL(prep_transpose_kernel,
                       dim3(TR_BLOCKS + WF_BLOCKS + BORDER_BLOCKS), dim3(256),
                       0, stream, x, offw, xPh, xPl, wF);
    hipLaunchKernelGGL(offset_mfma_kernel, dim3(512), dim3(256),
                       0, stream, xPh, xPl, wF, offb, sgrid);
    hipLaunchKernelGGL(sample_kernel, dim3(SAMPLE_BLOCKS), dim3(256),
                       0, stream, xPh, sgrid, wwk, out);
}

// Round 20
// 44.212 us; speedup vs baseline: 1.8874x; 1.0318x over previous
//
#include <hip/hip_runtime.h>

#define BB 8
#define CC 128
#define HH 64
#define WW 64
#define K2 9
#define NOFF 18
#define HW 4096          // HH*WW
#define NPIX 32768       // BB*HW
#define OPAD 32          // o padded to 32 (2 N-tiles)
#define HP 66            // padded spatial dim
#define PSTRIDE (HP*HP*CC)   // elems per batch (padded)

#define TR_BLOCKS     4096  // 128 p-tiles x 4 c-tiles x 8 b
#define WF_BLOCKS     288   // 144 frags x 512 elems / 256
#define BORDER_BLOCKS 260   // 2 bufs x 2080 cells x 16 uint4 / 256

#define GR_ROW 1056         // granules (16B) per row per buf: 66 px x 16
#define ROWSET_BYTES 33792  // 2 bufs x 1056 x 16

typedef __attribute__((ext_vector_type(8))) short bf16x8;
typedef __attribute__((ext_vector_type(4))) float f32x4;

__device__ __forceinline__ unsigned short f2bf(float f) {
    unsigned u = __float_as_uint(f);
    unsigned r = u + 0x7FFFu + ((u >> 16) & 1u);   // RNE
    return (unsigned short)(r >> 16);
}
__device__ __forceinline__ float bf2f(unsigned short h) {
    return __uint_as_float((unsigned)h << 16);
}

// ---------------------------------------------------------------------------
// K0: fused prep (R19-verified).
//  [0,TR)        : transpose x -> xPh/xPl (hi/lo, zero-padded [b][66][66][128])
//  [TR,+WF)      : weights -> wF fragment-major (contiguous 16B/lane reads)
//  [.., +BORDER) : zero the 1-px border of xPh/xPl
// ---------------------------------------------------------------------------
__global__ __launch_bounds__(256) void prep_transpose_kernel(
    const float* __restrict__ x, const float* __restrict__ offw,
    unsigned short* __restrict__ xPh, unsigned short* __restrict__ xPl,
    unsigned short* __restrict__ wF)
{
    __shared__ float tile[32][33];
    int bi = blockIdx.x;
    int tid = threadIdx.x;
    if (bi < TR_BLOCKS) {
        int p0 = (bi & 127) * 32;
        int c0 = ((bi >> 7) & 3) * 32;
        int b  = bi >> 9;
        int tx = tid & 31;
        int ty = tid >> 5;                 // 0..7
#pragma unroll
        for (int i = 0; i < 4; ++i)
            tile[ty + i * 8][tx] =
                x[((size_t)(b * CC + c0 + ty + i * 8)) * HW + p0 + tx];
        __syncthreads();
#pragma unroll
        for (int i = 0; i < 4; ++i) {
            int p = p0 + ty + i * 8;
            int h = p >> 6, w = p & 63;
            float v = tile[tx][ty + i * 8];
            unsigned short hi = f2bf(v);
            unsigned short lo = f2bf(v - bf2f(hi));
            size_t pidx = ((size_t)b * HP * HP + (size_t)(h + 1) * HP + (w + 1)) * CC + c0 + tx;
            xPh[pidx] = hi;
            xPl[pidx] = lo;
        }
    } else if (bi < TR_BLOCKS + WF_BLOCKS) {
        int e = (bi - TR_BLOCKS) * 256 + tid;   // 0..73727
        int fid = e >> 9;
        int r = e & 511;
        int lane = r >> 3;
        int elem = r & 7;
        int bufsel = fid & 1;
        int n   = (fid >> 1) & 1;
        int cwv = (fid >> 2) & 3;
        int j   = fid >> 4;
        int o = n * 16 + (lane & 15);
        int c = cwv * 32 + ((lane >> 4) << 3) + elem;
        float v = (o < NOFF) ? offw[((size_t)o * CC + c) * K2 + j] : 0.f;
        unsigned short hi = f2bf(v);
        wF[e] = bufsel ? f2bf(v - bf2f(hi)) : hi;
    } else {
        int i = (bi - TR_BLOCKS - WF_BLOCKS) * 256 + tid;   // 0..66559
        int bufsel = i >= 33280;
        int jj = i - bufsel * 33280;
        int cell = jj >> 4, q = jj & 15;
        int b = cell / 260, r = cell - b * 260;
        int hp, wp;
        if (r < 132) { hp = (r >= 66) ? (HP - 1) : 0; wp = (r >= 66) ? r - 66 : r; }
        else { int r2 = r - 132; wp = (r2 & 1) ? (HP - 1) : 0; hp = 1 + (r2 >> 1); }
        unsigned short* dst = bufsel ? xPl : xPh;
        uint4 z = {0u, 0u, 0u, 0u};
        *(uint4*)(dst + (((size_t)b * HP + hp) * HP + wp) * CC + q * 8) = z;
    }
}

// ---------------------------------------------------------------------------
// K1: FUSED offset-conv (MFMA, LDS-staged A — R19-verified) + bilinear
// sample for the same 64-px row. Phase 1: conv -> red[] (aliased over
// staging). Phase 2: 576 (tap,px) records computed ONCE per row into LDS
// (no sgrid round-trip). Phase 3: gather+tap-sum for 64 px x 128 ch in 4
// passes of the verified 16-px inner loop; acc_s aliases dead staging.
// ---------------------------------------------------------------------------
__global__ __launch_bounds__(256, 2) void fused_conv_sample_kernel(
    const unsigned short* __restrict__ xPh, const unsigned short* __restrict__ xPl,
    const unsigned short* __restrict__ wF, const float* __restrict__ offb,
    const float* __restrict__ wk, float* __restrict__ out)
{
    __shared__ __align__(16) unsigned char LDSB[ROWSET_BYTES];   // 33 KB (staging/red/acc_s)
    __shared__ float4 recW[576];   // 9.2 KB
    __shared__ int2   recI[576];   // 4.6 KB
    __shared__ float  swkT[K2 * CC];  // 4.6 KB
    int jx = blockIdx.x;        // 0..511
    int b = jx & 7;             // XCD-local batch
    int h = jx >> 3;            // 0..63
    int tid = threadIdx.x;
    int l = tid & 63;
    int cw = __builtin_amdgcn_readfirstlane(tid >> 6);   // 0..3 c-chunk
    int row  = l & 15;          // A: M-row ; B: o-col
    int kseg = l >> 4;          // 0..3
    int cslot = cw * 4 + kseg;  // 16B channel-slot

    // tap weights (transposed) — once per block
    for (int i = tid; i < K2 * CC; i += 256) {
        int c = i / 9, t = i - c * 9;
        swkT[t * CC + c] = wk[i];
    }

    f32x4 acc[4][2];
#pragma unroll
    for (int m = 0; m < 4; ++m)
#pragma unroll
        for (int n = 0; n < 2; ++n)
            acc[m][n] = (f32x4){0.f, 0.f, 0.f, 0.f};

    const unsigned short* xh = xPh + (size_t)b * PSTRIDE;
    const unsigned short* xl = xPl + (size_t)b * PSTRIDE;

    // ---------------- Phase 1: conv (R19 structure) ----------------
#pragma unroll 1
    for (int dh = 0; dh < 3; ++dh) {
        if (dh) __syncthreads();
        const unsigned short* rowh = xh + ((size_t)(h + dh) * HP) * CC;
        const unsigned short* rowl = xl + ((size_t)(h + dh) * HP) * CC;
#pragma unroll
        for (int it = 0; it < 9; ++it) {
            int G = it * 256 + tid;
            if (G < 2112) {
                int buf = G >= GR_ROW;
                int g = G - (buf ? GR_ROW : 0);
                int px = g >> 4, cg = g & 15;
                const unsigned short* src =
                    (buf ? rowl : rowh) + (size_t)px * CC + ((cg ^ (px & 7)) << 3);
                uint4 v = *(const uint4*)src;
                *(uint4*)(LDSB + (size_t)G * 16) = v;
            }
        }
        __syncthreads();
#pragma unroll
        for (int dw = 0; dw < 3; ++dw) {
            int j = dh * 3 + dw;
            int fbase = (j * 4 + cw) * 4;
            bf16x8 Bh0 = *(const bf16x8*)(wF + (size_t)(fbase + 0) * 512 + l * 8);
            bf16x8 Bl0 = *(const bf16x8*)(wF + (size_t)(fbase + 1) * 512 + l * 8);
            bf16x8 Bh1 = *(const bf16x8*)(wF + (size_t)(fbase + 2) * 512 + l * 8);
            bf16x8 Bl1 = *(const bf16x8*)(wF + (size_t)(fbase + 3) * 512 + l * 8);
#pragma unroll
            for (int m = 0; m < 4; ++m) {
                int px = m * 16 + row + dw;
                int gA = px * 16 + (cslot ^ (px & 7));
                bf16x8 Ah = *(const bf16x8*)(LDSB + (size_t)gA * 16);
                bf16x8 Al = *(const bf16x8*)(LDSB + (size_t)(GR_ROW + gA) * 16);
                acc[m][0] = __builtin_amdgcn_mfma_f32_16x16x32_bf16(Ah, Bh0, acc[m][0], 0, 0, 0);
                acc[m][0] = __builtin_amdgcn_mfma_f32_16x16x32_bf16(Al, Bh0, acc[m][0], 0, 0, 0);
                acc[m][0] = __builtin_amdgcn_mfma_f32_16x16x32_bf16(Ah, Bl0, acc[m][0], 0, 0, 0);
                acc[m][1] = __builtin_amdgcn_mfma_f32_16x16x32_bf16(Ah, Bh1, acc[m][1], 0, 0, 0);
                acc[m][1] = __builtin_amdgcn_mfma_f32_16x16x32_bf16(Al, Bh1, acc[m][1], 0, 0, 0);
                acc[m][1] = __builtin_amdgcn_mfma_f32_16x16x32_bf16(Ah, Bl1, acc[m][1], 0, 0, 0);
            }
        }
    }

    // ---------------- Phase 2: reduce + records (once per row) ----------------
    __syncthreads();
    float (*red)[OPAD][65] = (float (*)[OPAD][65])LDSB;   // aliases staging
#pragma unroll
    for (int m = 0; m < 4; ++m)
#pragma unroll
        for (int n = 0; n < 2; ++n)
#pragma unroll
            for (int r = 0; r < 4; ++r)
                red[cw][n * 16 + row][m * 16 + kseg * 4 + r] = acc[m][n][r];
    __syncthreads();

    float base_y = -1.f + (2.f / (HH - 1)) * (float)h;
    for (int item = tid; item < 576; item += 256) {
        int p = item & 63;
        int t = item >> 6;       // 0..8
        float sx = offb[t]
                 + red[0][t][p] + red[1][t][p] + red[2][t][p] + red[3][t][p];
        float sy = offb[t + K2]
                 + red[0][t + K2][p] + red[1][t + K2][p]
                 + red[2][t + K2][p] + red[3][t + K2][p];
        float base_x = -1.f + (2.f / (WW - 1)) * (float)p;
        float gx = ((sx + base_x + 1.f) * (float)WW - 1.f) * 0.5f;
        float gy = ((sy + base_y + 1.f) * (float)HH - 1.f) * 0.5f;

        float x0f = floorf(gx), y0f = floorf(gy);
        float wx1 = gx - x0f, wx0 = 1.f - wx1;
        float wy1 = gy - y0f, wy0 = 1.f - wy1;
        int ix0 = (int)x0f, iy0 = (int)y0f;
        int ix1 = ix0 + 1,  iy1 = iy0 + 1;
        float ax0 = ((unsigned)ix0 < WW) ? wx0 : 0.f;
        float ax1 = ((unsigned)ix1 < WW) ? wx1 : 0.f;
        float ay0 = ((unsigned)iy0 < HH) ? wy0 : 0.f;
        float ay1 = ((unsigned)iy1 < HH) ? wy1 : 0.f;
        int cx0 = min(max(ix0, 0), WW - 1) + 1, cx1 = min(max(ix1, 0), WW - 1) + 1;
        int cy0 = min(max(iy0, 0), HH - 1) + 1, cy1 = min(max(iy1, 0), HH - 1) + 1;
        int o00 = cy0 * HP + cx0, o10 = cy0 * HP + cx1;
        int o01 = cy1 * HP + cx0, o11 = cy1 * HP + cx1;
        recW[t * 64 + p] = make_float4(ax0 * ay0, ax1 * ay0, ax0 * ay1, ax1 * ay1);
        recI[t * 64 + p] = make_int2(o00 | (o10 << 16), o01 | (o11 << 16));
    }
    __syncthreads();

    // ---------------- Phase 3: gather + tap-weighted sum ----------------
    int c8     = (tid & 15) * 8;
    int slot16 = tid >> 4;           // 0..15
    const unsigned short* xb = xh;   // padded hi buffer
    float* acc_s = (float*)LDSB;     // 16*132 floats, aliases dead staging

    float4 wkA[K2], wkB[K2];
#pragma unroll
    for (int t = 0; t < K2; ++t) {
        wkA[t] = *(const float4*)&swkT[t * CC + c8];
        wkB[t] = *(const float4*)&swkT[t * CC + c8 + 4];
    }

#pragma unroll 1
    for (int pp = 0; pp < 4; ++pp) {
        int slot = pp * 16 + slot16;
        float acc8[8];
#pragma unroll
        for (int i = 0; i < 8; ++i) acc8[i] = 0.f;
#pragma unroll
        for (int t = 0; t < K2; ++t) {
            int r = t * 64 + slot;
            float4 wv = recW[r];
            int2   iv = recI[r];
            uint4 u00 = *(const uint4*)(xb + (((iv.x & 0xFFFF) << 7) + c8));
            uint4 u10 = *(const uint4*)(xb + (((iv.x >> 16)     << 7) + c8));
            uint4 u01 = *(const uint4*)(xb + (((iv.y & 0xFFFF) << 7) + c8));
            uint4 u11 = *(const uint4*)(xb + (((iv.y >> 16)     << 7) + c8));
            const unsigned* p00 = (const unsigned*)&u00;
            const unsigned* p10 = (const unsigned*)&u10;
            const unsigned* p01 = (const unsigned*)&u01;
            const unsigned* p11 = (const unsigned*)&u11;
#pragma unroll
            for (int g = 0; g < 4; ++g) {
                float v00a = __uint_as_float(p00[g] << 16);
                float v00b = __uint_as_float(p00[g] & 0xFFFF0000u);
                float v10a = __uint_as_float(p10[g] << 16);
                float v10b = __uint_as_float(p10[g] & 0xFFFF0000u);
                float v01a = __uint_as_float(p01[g] << 16);
                float v01b = __uint_as_float(p01[g] & 0xFFFF0000u);
                float v11a = __uint_as_float(p11[g] << 16);
                float v11b = __uint_as_float(p11[g] & 0xFFFF0000u);
                float bila = fmaf(v00a, wv.x, fmaf(v10a, wv.y, fmaf(v01a, wv.z, v11a * wv.w)));
                float bilb = fmaf(v00b, wv.x, fmaf(v10b, wv.y, fmaf(v01b, wv.z, v11b * wv.w)));
                float wka = (g < 2) ? ((g == 0) ? wkA[t].x : wkA[t].z)
                                    : ((g == 2) ? wkB[t].x : wkB[t].z);
                float wkb = (g < 2) ? ((g == 0) ? wkA[t].y : wkA[t].w)
                                    : ((g == 2) ? wkB[t].y : wkB[t].w);
                acc8[g * 2]     = fmaf(bila, wka, acc8[g * 2]);
                acc8[g * 2 + 1] = fmaf(bilb, wkb, acc8[g * 2 + 1]);
            }
        }
        __syncthreads();   // acc_s free (prev pp reads done / staging dead)
        *(float4*)&acc_s[slot16 * 132 + c8]     = make_float4(acc8[0], acc8[1], acc8[2], acc8[3]);
        *(float4*)&acc_s[slot16 * 132 + c8 + 4] = make_float4(acc8[4], acc8[5], acc8[6], acc8[7]);
        __syncthreads();
#pragma unroll
        for (int r = 0; r < 8; ++r) {
            int cs   = r * 16 + (tid >> 4);
            int wloc = tid & 15;
            out[((size_t)(b * CC + cs)) * HW + h * WW + pp * 16 + wloc] =
                acc_s[wloc * 132 + cs];
        }
    }
}

// ---------------------------------------------------------------------------
// Fallback (round-1 pipeline, needs only 2.36 MB ws) — defensive only.
// ---------------------------------------------------------------------------
__global__ __launch_bounds__(256) void offset_grid_kernel_fb(
    const float* __restrict__ x, const float* __restrict__ offw,
    const float* __restrict__ offb, float* __restrict__ grid)
{
    int idx = blockIdx.x * blockDim.x + threadIdx.x;
    if (idx >= NPIX) return;
    int w = idx & 63, h = (idx >> 6) & 63, b = idx >> 12;
    float acc[NOFF];
#pragma unroll
    for (int o = 0; o < NOFF; ++o) acc[o] = offb[o];
    for (int c = 0; c < CC; ++c) {
        const float* xp = x + ((size_t)(b * CC + c)) * HW;
        float xv[9];
#pragma unroll
        for (int dh = -1; dh <= 1; ++dh)
#pragma unroll
            for (int dw = -1; dw <= 1; ++dw) {
                int hh = h + dh, ww2 = w + dw;
                float v = 0.f;
                if (hh >= 0 && hh < HH && ww2 >= 0 && ww2 < WW) v = xp[hh * WW + ww2];
                xv[(dh + 1) * 3 + (dw + 1)] = v;
            }
#pragma unroll
        for (int o = 0; o < NOFF; ++o) {
            const float* wp = offw + (size_t)(o * CC + c) * 9;
#pragma unroll
            for (int jj = 0; jj < 9; ++jj) acc[o] = fmaf(xv[jj], wp[jj], acc[o]);
        }
    }
    float base_x = -1.f + (2.f / (WW - 1)) * (float)w;
    float base_y = -1.f + (2.f / (HH - 1)) * (float)h;
#pragma unroll
    for (int t = 0; t < K2; ++t) {
        float gx = ((acc[t]      + base_x + 1.f) * (float)WW - 1.f) * 0.5f;
        float gy = ((acc[K2 + t] + base_y + 1.f) * (float)HH - 1.f) * 0.5f;
        size_t gi = ((((size_t)b * K2 + t) * HH + h) * WW + w) * 2;
        grid[gi] = gx; grid[gi + 1] = gy;
    }
}

__global__ __launch_bounds__(256) void sample_kernel_fb(
    const float* __restrict__ x, const float* __restrict__ grid,
    const float* __restrict__ wk, float* __restrict__ out)
{
    int idx = blockIdx.x * blockDim.x + threadIdx.x;
    if (idx >= BB * CC * HW) return;
    int w = idx & 63, h = (idx >> 6) & 63;
    int c = (idx / HW) & 127, b = idx / (CC * HW);
    const float* xp = x + ((size_t)(b * CC + c)) * HW;
    const float2* gp = (const float2*)grid;
    float acc = 0.f;
#pragma unroll
    for (int t = 0; t < K2; ++t) {
        float2 g = gp[(((size_t)b * K2 + t)) * HW + h * WW + w];
        float gx = g.x, gy = g.y;
        float x0f = floorf(gx), y0f = floorf(gy);
        float wx1 = gx - x0f, wx0 = 1.f - wx1;
        float wy1 = gy - y0f, wy0 = 1.f - wy1;
        int ix0 = (int)x0f, iy0 = (int)y0f;
        int ix1 = ix0 + 1,  iy1 = iy0 + 1;
        float v00 = 0.f, v10 = 0.f, v01 = 0.f, v11 = 0.f;
        if ((unsigned)iy0 < HH) {
            const float* row = xp + (size_t)iy0 * WW;
            if ((unsigned)ix0 < WW) v00 = row[ix0];
            if ((unsigned)ix1 < WW) v10 = row[ix1];
        }
        if ((unsigned)iy1 < HH) {
            const float* row = xp + (size_t)iy1 * WW;
            if ((unsigned)ix0 < WW) v01 = row[ix0];
            if ((unsigned)ix1 < WW) v11 = row[ix1];
        }
        float bil = v00 * (wx0 * wy0) + v10 * (wx1 * wy0)
                  + v01 * (wx0 * wy1) + v11 * (wx1 * wy1);
        acc = fmaf(bil, wk[c * K2 + t], acc);
    }
    out[idx] = acc;
}

extern "C" void kernel_launch(void* const* d_in, const int* in_sizes, int n_in,
                              void* d_out, int out_size, void* d_ws, size_t ws_size,
                              hipStream_t stream) {
    const float* x    = (const float*)d_in[0];
    const float* offw = (const float*)d_in[1];
    const float* offb = (const float*)d_in[2];
    const float* wwk  = (const float*)d_in[3];
    float* out = (float*)d_out;

    const size_t XP_BYTES = (size_t)BB * PSTRIDE * sizeof(unsigned short); // 8.92 MB
    const size_t WF_BYTES = (size_t)144 * 512 * sizeof(unsigned short);    // 147 KB
    const size_t NEED = 2 * XP_BYTES + WF_BYTES;                           // 18.0 MB

    if (ws_size < NEED) {
        float* grid = (float*)d_ws;
        hipLaunchKernelGGL(offset_grid_kernel_fb, dim3(NPIX / 256), dim3(256),
                           0, stream, x, offw, offb, grid);
        hipLaunchKernelGGL(sample_kernel_fb, dim3((BB * CC * HW) / 256), dim3(256),
                           0, stream, x, grid, wwk, out);
        return;
    }

    // ws: [xPh][xPl][wF]
    char* p = (char*)d_ws;
    unsigned short* xPh = (unsigned short*)p;           p += XP_BYTES;
    unsigned short* xPl = (unsigned short*)p;           p += XP_BYTES;
    unsigned short* wF  = (unsigned short*)p;

    hipLaunchKernelGGL(prep_transpose_kernel,
                       dim3(TR_BLOCKS + WF_BLOCKS + BORDER_BLOCKS), dim3(256),
                       0, stream, x, offw, xPh, xPl, wF);
    hipLaunchKernelGGL(fused_conv_sample_kernel, dim3(512), dim3(256),
                       0, stream, xPh, xPl, wF, offb, wwk, out);
}